// Round 19
// baseline (3715.363 us; speedup 1.0000x reference)
//
#include <hip/hip_runtime.h>
#include <hip/hip_bf16.h>

#define NSWEEP_X 5
#define NSWEEP_W 9

typedef float v2f __attribute__((ext_vector_type(2)));

__device__ __forceinline__ void wavefence() {
    __builtin_amdgcn_wave_barrier();
    asm volatile("" ::: "memory");
}

// Packed fp32 (VOP3P) helpers — 2 fp32 per instruction.
__device__ __forceinline__ v2f pk_mul(v2f a, v2f b) {
    v2f d; asm("v_pk_mul_f32 %0, %1, %2" : "=v"(d) : "v"(a), "v"(b)); return d;
}
__device__ __forceinline__ v2f pk_add(v2f a, v2f b) {
    v2f d; asm("v_pk_add_f32 %0, %1, %2" : "=v"(d) : "v"(a), "v"(b)); return d;
}
__device__ __forceinline__ v2f pk_fma(v2f a, v2f b, v2f c) {
    v2f d; asm("v_pk_fma_f32 %0, %1, %2, %3" : "=v"(d) : "v"(a), "v"(b), "v"(c)); return d;
}

__device__ __forceinline__ float bperm(int addr, float v) {
    return __int_as_float(__builtin_amdgcn_ds_bpermute(addr, __float_as_int(v)));
}

// DPP xor-lane read: out[l] = in[l ^ mask] (masks<16 stay in 16-lane rows).
// Codes (r12/r14/r16/r18-verified): xor1=0xB1 xor2=0x4E xor3=0x1B xor7=0x141
// xor8=0x128(row_ror:8) xor15=0x140(row_mirror); composed pair = mask XOR.
// Pipe calibration (r16 k=9: 833us VALU-bound; r17 k=0: 991us DS-bound;
// r18 k=6: 753us balanced) -> keep k=6.
template<int C1, int C2>
__device__ __forceinline__ float dppf(float v) {
    int x = __builtin_amdgcn_mov_dpp(__float_as_int(v), C1, 0xF, 0xF, false);
    if constexpr (C2 >= 0)
        x = __builtin_amdgcn_mov_dpp(x, C2, 0xF, 0xF, false);
    return __int_as_float(x);
}

// 4-accumulator dot of two 32-float columns held as v2f[16].
__device__ __forceinline__ float dot32(const v2f a[16], const v2f b[16]) {
    v2f s0 = pk_mul(a[0], b[0]), s1 = pk_mul(a[1], b[1]);
    v2f s2 = pk_mul(a[2], b[2]), s3 = pk_mul(a[3], b[3]);
#pragma unroll
    for (int i = 4; i < 16; i += 4) {
        s0 = pk_fma(a[i+0], b[i+0], s0);
        s1 = pk_fma(a[i+1], b[i+1], s1);
        s2 = pk_fma(a[i+2], b[i+2], s2);
        s3 = pk_fma(a[i+3], b[i+3], s3);
    }
    v2f s = pk_add(pk_add(s0, s1), pk_add(s2, s3));
    return s.x + s.y;
}

// BRANCHLESS rotation core — r14/r16/r18-proven (64 VGPR, zero scratch).
// SPILL RULE (r3/r12/r15): prt[16] must be consumed in STRAIGHT-LINE code.
// Any branch/switch/unroll putting the array live across a CFG join demotes
// it to scratch (r15: one `if` around the apply -> 22.6 GB scratch, 7x).
// Per-lane skip is v_cndmask only: t=0 -> cth=1, s=0 -> bitwise identity.
// No EXEC-mask writes (r13 hazard: EXEC write before DPP read -> stale data).
// Local-tau (r7+): col' = c*col - s*prt, nn' = nn - t*cp, side-uniform;
// cp bitwise-equal across the pair -> symmetric decisions.
__device__ __forceinline__ int round_core(v2f col[16], const v2f prt[16],
                                          float& nn, float on, float thr) {
    float cp = dot32(col, prt);
    const bool rot = (cp * cp > thr);
    float tau = (on - nn) * __builtin_amdgcn_rcpf(2.0f * cp);
    float den = fabsf(tau) + __builtin_amdgcn_sqrtf(fmaf(tau, tau, 1.0f));
    float tt  = copysignf(__builtin_amdgcn_rcpf(den), tau);
    tt = rot ? tt : 0.0f;                              // v_cndmask, no EXEC write
    float cth = __builtin_amdgcn_rsqf(fmaf(tt, tt, 1.0f));   // tt=0 -> exactly 1.0
    float msn = tt * (-cth);
    v2f cs2; cs2.x = cth; cs2.y = cth;
    v2f ms2; ms2.x = msn; ms2.y = msn;
#pragma unroll
    for (int i = 0; i < 16; i++)
        col[i] = pk_fma(ms2, prt[i], pk_mul(cs2, col[i]));
    nn = fmaxf(fmaf(-tt, cp, nn), 0.0f);
    return rot ? 1 : 0;
}

// DPP round: partner fetch on the VALU pipe (zero DS ops). Fresh prt[16]
// per inlined body, consumed straight-line (SPILL RULE).
template<int C1, int C2>
__device__ __forceinline__ int round_dpp(v2f col[16], float& nn, float thr) {
    v2f prt[16];
#pragma unroll
    for (int i = 0; i < 16; i++) {
        prt[i].x = dppf<C1, C2>(col[i].x);
        prt[i].y = dppf<C1, C2>(col[i].y);
    }
    float on = dppf<C1, C2>(nn);
    return round_core(col, prt, nn, on, thr);
}

// bpermute round (DS pipe).
__device__ __forceinline__ int round_bperm(v2f col[16], float& nn, float thr,
                                           int lb, int m) {
    const int addr = lb ^ (m << 2);                    // within own 32-lane half
    v2f prt[16];
#pragma unroll
    for (int i = 0; i < 16; i++) {
        prt[i].x = bperm(addr, col[i].x);
        prt[i].y = bperm(addr, col[i].y);
    }
    float on = bperm(addr, nn);
    return round_core(col, prt, nn, on, thr);
}

// One-sided Jacobi, FULL column per lane, TWO matrices per wave (32-lane
// halves). XOR ordering over all m=1..31 (any fixed order = valid sweep).
// PIPE-BALANCED hybrid (r16/r17/r18 calibration): 6 single-op DPP
// {1,2,3,7,8,15} + 6 composed-DPP {4,5,6,9,10,11} on VALU; 19 masks
// {12,13,14,16..31} on DS via bpermute.
// Absolute skip threshold (4e-6*nmax)^2 above fp32 dot noise; all-skip
// early exit is a uniform SALU branch.
__device__ __forceinline__ void jacobi_hyb(v2f col[16], int lane, int nsweep) {
    const int lb = lane << 2;
    for (int sw = 0; sw < nsweep; ++sw) {
        float nn = dot32(col, col);
        float nmax = nn;
#pragma unroll
        for (int mk = 16; mk >= 1; mk >>= 1) nmax = fmaxf(nmax, __shfl_xor(nmax, mk));
        const float thr = 1.6e-11f * nmax * nmax;   // (4e-6 * nmax)^2

        int did = 0;
        did |= round_dpp<0xB1,  -1>(col, nn, thr);    // m=1
        did |= round_dpp<0x4E,  -1>(col, nn, thr);    // m=2
        did |= round_dpp<0x1B,  -1>(col, nn, thr);    // m=3
        did |= round_dpp<0x141, -1>(col, nn, thr);    // m=7
        did |= round_dpp<0x128, -1>(col, nn, thr);    // m=8
        did |= round_dpp<0x140, -1>(col, nn, thr);    // m=15
        did |= round_dpp<0x141, 0x1B>(col, nn, thr);  // m=4  (7^3)
        did |= round_dpp<0x141, 0x4E>(col, nn, thr);  // m=5  (7^2)
        did |= round_dpp<0x141, 0xB1>(col, nn, thr);  // m=6  (7^1)
        did |= round_dpp<0x128, 0xB1>(col, nn, thr);  // m=9  (8^1)
        did |= round_dpp<0x128, 0x4E>(col, nn, thr);  // m=10 (8^2)
        did |= round_dpp<0x128, 0x1B>(col, nn, thr);  // m=11 (8^3)
#pragma unroll 1
        for (int m = 12; m < 15; ++m)             // m=12,13,14
            did |= round_bperm(col, nn, thr, lb, m);
#pragma unroll 1
        for (int m = 16; m < 32; ++m)             // m=16..31
            did |= round_bperm(col, nn, thr, lb, m);

        if (!__any(did)) break;   // converged (uniform branch)
    }
}

// Rank own column by sigma^2 (descending, tie-break index) within the 32-lane
// group; rk<8 lanes pack their column into P0m[rk*32 + h], sigma^2 into sigm.
__device__ __forceinline__ void rank_pack2(const v2f col[16], int jl,
                                           float* P0m, float* nrmm, float* sigm) {
    float nn = dot32(col, col);
    nrmm[jl] = nn;
    wavefence();
    int rk = 0;
    for (int k = 0; k < 32; k++) {
        float o = nrmm[k];
        rk += (o > nn) || (o == nn && k < jl);
    }
    if (rk < 8) {
#pragma unroll
        for (int i = 0; i < 16; i++)
            *(v2f*)&P0m[rk * 32 + 2 * i] = col[i];
        sigm[rk] = nn;
    }
    wavefence();
}

// ---- Kernel 1: SVD of w[c]; one wave per block handles TWO c channels.
//   uwd[c][h][m] = Uw[h][m]*dw[m]   (converged column)
//   vwt[c][w][m] = Vwh[m][w]        (A0^T a_m / sigma_m^2)
__global__ __launch_bounds__(64)
void svd_w_kernel(const float* __restrict__ w, float* __restrict__ uwd,
                  float* __restrict__ vwt) {
    __shared__ float P0w[512];   // [hb*256 + mm*32 + h]
    __shared__ float nrmw[64];
    __shared__ float sigw[16];
    const int lane = threadIdx.x, jl = lane & 31, hb = lane >> 5;
    const int c = blockIdx.x * 2 + hb;

    v2f col[16], a0[16];
#pragma unroll
    for (int i = 0; i < 16; i++) {
        col[i].x = w[c * 1024 + (2 * i) * 32 + jl];
        col[i].y = w[c * 1024 + (2 * i + 1) * 32 + jl];
        a0[i] = col[i];
    }
    jacobi_hyb(col, lane, NSWEEP_W);
    rank_pack2(col, jl, P0w + hb * 256, nrmw + hb * 32, sigw + hb * 8);

    for (int e = jl; e < 256; e += 32)
        uwd[c * 256 + e] = P0w[hb * 256 + (e & 7) * 32 + (e >> 3)];

#pragma unroll
    for (int mm = 0; mm < 8; mm++) {
        v2f p[16];
#pragma unroll
        for (int i = 0; i < 16; i++) p[i] = *(const v2f*)&P0w[hb * 256 + mm * 32 + 2 * i];
        float vq = dot32(a0, p);
        vq *= __builtin_amdgcn_rcpf(sigw[hb * 8 + mm]);
        vwt[c * 256 + jl * 8 + mm] = vq;
    }
}

// ---- Kernel 2: block = 4 waves = 8 matrices (8 c of one bt). grid 4096.
// No LDS staging (global strided loads; input is L3-resident). a0 re-loaded
// from global after Jacobi -> no a0 liveness across the sweep.
// launch_bounds(256,8): request 8 blocks/CU residency — VGPR=64 is exactly
// the 8-waves/SIMD budget and LDS 17.9KB fits 8 blocks; r18's (256,4) left
// occupancy at 42% while both pipes sat at ~60% (latency-residual regime).
__global__ __launch_bounds__(256, 8)
void svd_main_kernel(const float* __restrict__ x, const float* __restrict__ uwd,
                     const float* __restrict__ vwt, float* __restrict__ out) {
    __shared__ float P0[2048];    // [mi*256 + mm*32 + h]
    __shared__ float nrm[256];    // [mi*32 + j]
    __shared__ float sig[64];     // [mi*8 + mm]
    __shared__ float OUT[2048];   // [mi*256 + i*32 + wj]  (8-row quarter-pass)

    const int t = threadIdx.x, widx = t >> 6, lane = t & 63;
    const int jl = lane & 31, hb = lane >> 5;
    const int bt = blockIdx.x & 1023, cg = blockIdx.x >> 10;
    const int mi = widx * 2 + hb, c = cg * 8 + mi;

    // own column straight from global: x[bt][h][jl][c], h stride 1024 floats
    const float* xb = x + (size_t)bt * 32768 + (size_t)jl * 32 + c;
    v2f col[16];
#pragma unroll
    for (int i = 0; i < 16; i++) {
        col[i].x = xb[(2 * i) * 1024];
        col[i].y = xb[(2 * i + 1) * 1024];
    }

    jacobi_hyb(col, lane, NSWEEP_X);
    rank_pack2(col, jl, P0 + mi * 256, nrm + mi * 32, sig + mi * 8);
    // col dead; re-load original column (L3-hot) for the V recovery

    v2f a0[16];
#pragma unroll
    for (int i = 0; i < 16; i++) {
        a0[i].x = xb[(2 * i) * 1024];
        a0[i].y = xb[(2 * i + 1) * 1024];
    }

    // qv[mm] = (A0^T a_mm / sigma^2) * vw   (lane jl = V-row index w)
    const float* vw = vwt + c * 256;
    const float* uw = uwd + c * 256;
    float qv[8];
#pragma unroll
    for (int mm = 0; mm < 8; mm++) {
        v2f p[16];
#pragma unroll
        for (int i = 0; i < 16; i++) p[i] = *(const v2f*)&P0[mi * 256 + mm * 32 + 2 * i];
        float vq = dot32(a0, p);
        vq *= __builtin_amdgcn_rcpf(sig[mi * 8 + mm]);
        qv[mm] = vq * vw[jl * 8 + mm];
    }

    // Pg in place: P0[mm*32+h] *= uw[h*8+mm]
    for (int e = jl; e < 256; e += 32)
        P0[mi * 256 + e] *= uw[(e & 31) * 8 + (e >> 5)];
    wavefence();

    // out[h][jl] = sum_mm Pg[h][mm]*qv[mm], in four 8-row quarter-passes.
    float4* o4 = (float4*)out;
    const size_t obase = (size_t)bt * 8192 + cg * 2;
    for (int p = 0; p < 4; ++p) {
#pragma unroll
        for (int i = 0; i < 8; i++) {
            int h = p * 8 + i;
            float acc = 0.f;
#pragma unroll
            for (int mm = 0; mm < 8; mm++)
                acc = fmaf(P0[mi * 256 + mm * 32 + h], qv[mm], acc);
            OUT[mi * 256 + i * 32 + jl] = acc;
        }
        __syncthreads();
        {
            int hh = t >> 5, wj = t & 31;         // 8 rows x 32 cols
            int h = p * 8 + hh;
            float4 v0 = make_float4(OUT[t], OUT[256 + t], OUT[512 + t], OUT[768 + t]);
            float4 v1 = make_float4(OUT[1024 + t], OUT[1280 + t], OUT[1536 + t], OUT[1792 + t]);
            o4[obase + (size_t)(h * 256 + wj * 8)]     = v0;
            o4[obase + (size_t)(h * 256 + wj * 8) + 1] = v1;
        }
        if (p < 3) __syncthreads();   // stores read OUT before next pass rewrites
    }
}

extern "C" void kernel_launch(void* const* d_in, const int* in_sizes, int n_in,
                              void* d_out, int out_size, void* d_ws, size_t ws_size,
                              hipStream_t stream) {
    (void)in_sizes; (void)n_in; (void)out_size; (void)ws_size;
    const float* x = (const float*)d_in[0];
    const float* w = (const float*)d_in[1];
    float* out = (float*)d_out;
    float* uwd = (float*)d_ws;            // [32][32][8]
    float* vwt = uwd + 32 * 256;          // [32][32][8]

    hipLaunchKernelGGL(svd_w_kernel, dim3(16), dim3(64), 0, stream, w, uwd, vwt);
    hipLaunchKernelGGL(svd_main_kernel, dim3(4096), dim3(256), 0, stream, x, uwd, vwt, out);
}

// Round 20
// 777.261 us; speedup vs baseline: 4.7801x; 4.7801x over previous
//
#include <hip/hip_runtime.h>
#include <hip/hip_bf16.h>

#define NSWEEP_X 5
#define NSWEEP_W 9

typedef float v2f __attribute__((ext_vector_type(2)));

__device__ __forceinline__ void wavefence() {
    __builtin_amdgcn_wave_barrier();
    asm volatile("" ::: "memory");
}

// Packed fp32 (VOP3P) helpers — 2 fp32 per instruction.
__device__ __forceinline__ v2f pk_mul(v2f a, v2f b) {
    v2f d; asm("v_pk_mul_f32 %0, %1, %2" : "=v"(d) : "v"(a), "v"(b)); return d;
}
__device__ __forceinline__ v2f pk_add(v2f a, v2f b) {
    v2f d; asm("v_pk_add_f32 %0, %1, %2" : "=v"(d) : "v"(a), "v"(b)); return d;
}
__device__ __forceinline__ v2f pk_fma(v2f a, v2f b, v2f c) {
    v2f d; asm("v_pk_fma_f32 %0, %1, %2, %3" : "=v"(d) : "v"(a), "v"(b), "v"(c)); return d;
}

__device__ __forceinline__ float bperm(int addr, float v) {
    return __int_as_float(__builtin_amdgcn_ds_bpermute(addr, __float_as_int(v)));
}

// DPP xor-lane read: out[l] = in[l ^ mask] (masks<16 stay in 16-lane rows).
// Codes (r12/r14/r16/r18-verified): xor1=0xB1 xor2=0x4E xor3=0x1B xor7=0x141
// xor8=0x128(row_ror:8) xor15=0x140(row_mirror); composed pair = mask XOR.
// Pipe calibration (r16 k=9: 833us VALU-bound; r17 k=0: 991us DS-bound;
// r18 k=6: 753us balanced) -> keep k=6.
template<int C1, int C2>
__device__ __forceinline__ float dppf(float v) {
    int x = __builtin_amdgcn_mov_dpp(__float_as_int(v), C1, 0xF, 0xF, false);
    if constexpr (C2 >= 0)
        x = __builtin_amdgcn_mov_dpp(x, C2, 0xF, 0xF, false);
    return __int_as_float(x);
}

// 4-accumulator dot of two 32-float columns held as v2f[16].
__device__ __forceinline__ float dot32(const v2f a[16], const v2f b[16]) {
    v2f s0 = pk_mul(a[0], b[0]), s1 = pk_mul(a[1], b[1]);
    v2f s2 = pk_mul(a[2], b[2]), s3 = pk_mul(a[3], b[3]);
#pragma unroll
    for (int i = 4; i < 16; i += 4) {
        s0 = pk_fma(a[i+0], b[i+0], s0);
        s1 = pk_fma(a[i+1], b[i+1], s1);
        s2 = pk_fma(a[i+2], b[i+2], s2);
        s3 = pk_fma(a[i+3], b[i+3], s3);
    }
    v2f s = pk_add(pk_add(s0, s1), pk_add(s2, s3));
    return s.x + s.y;
}

// BRANCHLESS rotation core — r14/r16/r18-proven (64 VGPR, zero scratch).
// SPILL RULE (r3/r12/r15/r19): prt[16] must be consumed in STRAIGHT-LINE
// code AND the VGPR bound must leave >=64 regs (r19: (256,8) capped VGPR at
// 32 -> 10 GB scratch, 5x regression). Per-lane skip is v_cndmask only:
// t=0 -> cth=1, s=0 -> bitwise identity. No EXEC-mask writes (r13 hazard).
// Local-tau (r7+): col' = c*col - s*prt, nn' = nn - t*cp, side-uniform;
// cp bitwise-equal across the pair -> symmetric decisions.
__device__ __forceinline__ int round_core(v2f col[16], const v2f prt[16],
                                          float& nn, float on, float thr) {
    float cp = dot32(col, prt);
    const bool rot = (cp * cp > thr);
    float tau = (on - nn) * __builtin_amdgcn_rcpf(2.0f * cp);
    float den = fabsf(tau) + __builtin_amdgcn_sqrtf(fmaf(tau, tau, 1.0f));
    float tt  = copysignf(__builtin_amdgcn_rcpf(den), tau);
    tt = rot ? tt : 0.0f;                              // v_cndmask, no EXEC write
    float cth = __builtin_amdgcn_rsqf(fmaf(tt, tt, 1.0f));   // tt=0 -> exactly 1.0
    float msn = tt * (-cth);
    v2f cs2; cs2.x = cth; cs2.y = cth;
    v2f ms2; ms2.x = msn; ms2.y = msn;
#pragma unroll
    for (int i = 0; i < 16; i++)
        col[i] = pk_fma(ms2, prt[i], pk_mul(cs2, col[i]));
    nn = fmaxf(fmaf(-tt, cp, nn), 0.0f);
    return rot ? 1 : 0;
}

// DPP round: partner fetch on the VALU pipe (zero DS ops). Fresh prt[16]
// per inlined body, consumed straight-line (SPILL RULE).
template<int C1, int C2>
__device__ __forceinline__ int round_dpp(v2f col[16], float& nn, float thr) {
    v2f prt[16];
#pragma unroll
    for (int i = 0; i < 16; i++) {
        prt[i].x = dppf<C1, C2>(col[i].x);
        prt[i].y = dppf<C1, C2>(col[i].y);
    }
    float on = dppf<C1, C2>(nn);
    return round_core(col, prt, nn, on, thr);
}

// bpermute round (DS pipe).
__device__ __forceinline__ int round_bperm(v2f col[16], float& nn, float thr,
                                           int lb, int m) {
    const int addr = lb ^ (m << 2);                    // within own 32-lane half
    v2f prt[16];
#pragma unroll
    for (int i = 0; i < 16; i++) {
        prt[i].x = bperm(addr, col[i].x);
        prt[i].y = bperm(addr, col[i].y);
    }
    float on = bperm(addr, nn);
    return round_core(col, prt, nn, on, thr);
}

// One-sided Jacobi, FULL column per lane, TWO matrices per wave (32-lane
// halves). XOR ordering over all m=1..31 (any fixed order = valid sweep).
// PIPE-BALANCED hybrid (r16/r17/r18 calibration): 6 single-op DPP
// {1,2,3,7,8,15} + 6 composed-DPP {4,5,6,9,10,11} on VALU; 19 masks
// {12,13,14,16..31} on DS via bpermute.
// Absolute skip threshold (4e-6*nmax)^2 above fp32 dot noise; all-skip
// early exit is a uniform SALU branch.
__device__ __forceinline__ void jacobi_hyb(v2f col[16], int lane, int nsweep) {
    const int lb = lane << 2;
    for (int sw = 0; sw < nsweep; ++sw) {
        float nn = dot32(col, col);
        float nmax = nn;
#pragma unroll
        for (int mk = 16; mk >= 1; mk >>= 1) nmax = fmaxf(nmax, __shfl_xor(nmax, mk));
        const float thr = 1.6e-11f * nmax * nmax;   // (4e-6 * nmax)^2

        int did = 0;
        did |= round_dpp<0xB1,  -1>(col, nn, thr);    // m=1
        did |= round_dpp<0x4E,  -1>(col, nn, thr);    // m=2
        did |= round_dpp<0x1B,  -1>(col, nn, thr);    // m=3
        did |= round_dpp<0x141, -1>(col, nn, thr);    // m=7
        did |= round_dpp<0x128, -1>(col, nn, thr);    // m=8
        did |= round_dpp<0x140, -1>(col, nn, thr);    // m=15
        did |= round_dpp<0x141, 0x1B>(col, nn, thr);  // m=4  (7^3)
        did |= round_dpp<0x141, 0x4E>(col, nn, thr);  // m=5  (7^2)
        did |= round_dpp<0x141, 0xB1>(col, nn, thr);  // m=6  (7^1)
        did |= round_dpp<0x128, 0xB1>(col, nn, thr);  // m=9  (8^1)
        did |= round_dpp<0x128, 0x4E>(col, nn, thr);  // m=10 (8^2)
        did |= round_dpp<0x128, 0x1B>(col, nn, thr);  // m=11 (8^3)
#pragma unroll 1
        for (int m = 12; m < 15; ++m)             // m=12,13,14
            did |= round_bperm(col, nn, thr, lb, m);
#pragma unroll 1
        for (int m = 16; m < 32; ++m)             // m=16..31
            did |= round_bperm(col, nn, thr, lb, m);

        if (!__any(did)) break;   // converged (uniform branch)
    }
}

// Rank own column by sigma^2 (descending, tie-break index) within the 32-lane
// group; rk<8 lanes pack their column into P0m[rk*32 + h], sigma^2 into sigm.
__device__ __forceinline__ void rank_pack2(const v2f col[16], int jl,
                                           float* P0m, float* nrmm, float* sigm) {
    float nn = dot32(col, col);
    nrmm[jl] = nn;
    wavefence();
    int rk = 0;
    for (int k = 0; k < 32; k++) {
        float o = nrmm[k];
        rk += (o > nn) || (o == nn && k < jl);
    }
    if (rk < 8) {
#pragma unroll
        for (int i = 0; i < 16; i++)
            *(v2f*)&P0m[rk * 32 + 2 * i] = col[i];
        sigm[rk] = nn;
    }
    wavefence();
}

// ---- Kernel 1: SVD of w[c]; one wave per block handles TWO c channels.
//   uwd[c][h][m] = Uw[h][m]*dw[m]   (converged column)
//   vwt[c][w][m] = Vwh[m][w]        (A0^T a_m / sigma_m^2)
__global__ __launch_bounds__(64)
void svd_w_kernel(const float* __restrict__ w, float* __restrict__ uwd,
                  float* __restrict__ vwt) {
    __shared__ float P0w[512];   // [hb*256 + mm*32 + h]
    __shared__ float nrmw[64];
    __shared__ float sigw[16];
    const int lane = threadIdx.x, jl = lane & 31, hb = lane >> 5;
    const int c = blockIdx.x * 2 + hb;

    v2f col[16], a0[16];
#pragma unroll
    for (int i = 0; i < 16; i++) {
        col[i].x = w[c * 1024 + (2 * i) * 32 + jl];
        col[i].y = w[c * 1024 + (2 * i + 1) * 32 + jl];
        a0[i] = col[i];
    }
    jacobi_hyb(col, lane, NSWEEP_W);
    rank_pack2(col, jl, P0w + hb * 256, nrmw + hb * 32, sigw + hb * 8);

    for (int e = jl; e < 256; e += 32)
        uwd[c * 256 + e] = P0w[hb * 256 + (e & 7) * 32 + (e >> 3)];

#pragma unroll
    for (int mm = 0; mm < 8; mm++) {
        v2f p[16];
#pragma unroll
        for (int i = 0; i < 16; i++) p[i] = *(const v2f*)&P0w[hb * 256 + mm * 32 + 2 * i];
        float vq = dot32(a0, p);
        vq *= __builtin_amdgcn_rcpf(sigw[hb * 8 + mm]);
        vwt[c * 256 + jl * 8 + mm] = vq;
    }
}

// ---- Kernel 2: block = 4 waves = 8 matrices (8 c of one bt). grid 4096.
// No LDS staging (global strided loads; input is L3-resident). a0 re-loaded
// from global after Jacobi -> no a0 liveness across the sweep.
// launch_bounds(256,6): 6 blocks/CU -> VGPR cap 85 >= the code's 64 (no
// spill), LDS 6x17.9KB < 160KB. r18 (256,4) = 42% occupancy both-pipes-60%;
// r19 (256,8) = VGPR crushed to 32 -> 10GB scratch. (256,6) is the bracket
// midpoint: +50% occupancy at zero register pressure.
__global__ __launch_bounds__(256, 6)
void svd_main_kernel(const float* __restrict__ x, const float* __restrict__ uwd,
                     const float* __restrict__ vwt, float* __restrict__ out) {
    __shared__ float P0[2048];    // [mi*256 + mm*32 + h]
    __shared__ float nrm[256];    // [mi*32 + j]
    __shared__ float sig[64];     // [mi*8 + mm]
    __shared__ float OUT[2048];   // [mi*256 + i*32 + wj]  (8-row quarter-pass)

    const int t = threadIdx.x, widx = t >> 6, lane = t & 63;
    const int jl = lane & 31, hb = lane >> 5;
    const int bt = blockIdx.x & 1023, cg = blockIdx.x >> 10;
    const int mi = widx * 2 + hb, c = cg * 8 + mi;

    // own column straight from global: x[bt][h][jl][c], h stride 1024 floats
    const float* xb = x + (size_t)bt * 32768 + (size_t)jl * 32 + c;
    v2f col[16];
#pragma unroll
    for (int i = 0; i < 16; i++) {
        col[i].x = xb[(2 * i) * 1024];
        col[i].y = xb[(2 * i + 1) * 1024];
    }

    jacobi_hyb(col, lane, NSWEEP_X);
    rank_pack2(col, jl, P0 + mi * 256, nrm + mi * 32, sig + mi * 8);
    // col dead; re-load original column (L3-hot) for the V recovery

    v2f a0[16];
#pragma unroll
    for (int i = 0; i < 16; i++) {
        a0[i].x = xb[(2 * i) * 1024];
        a0[i].y = xb[(2 * i + 1) * 1024];
    }

    // qv[mm] = (A0^T a_mm / sigma^2) * vw   (lane jl = V-row index w)
    const float* vw = vwt + c * 256;
    const float* uw = uwd + c * 256;
    float qv[8];
#pragma unroll
    for (int mm = 0; mm < 8; mm++) {
        v2f p[16];
#pragma unroll
        for (int i = 0; i < 16; i++) p[i] = *(const v2f*)&P0[mi * 256 + mm * 32 + 2 * i];
        float vq = dot32(a0, p);
        vq *= __builtin_amdgcn_rcpf(sig[mi * 8 + mm]);
        qv[mm] = vq * vw[jl * 8 + mm];
    }

    // Pg in place: P0[mm*32+h] *= uw[h*8+mm]
    for (int e = jl; e < 256; e += 32)
        P0[mi * 256 + e] *= uw[(e & 31) * 8 + (e >> 5)];
    wavefence();

    // out[h][jl] = sum_mm Pg[h][mm]*qv[mm], in four 8-row quarter-passes.
    float4* o4 = (float4*)out;
    const size_t obase = (size_t)bt * 8192 + cg * 2;
    for (int p = 0; p < 4; ++p) {
#pragma unroll
        for (int i = 0; i < 8; i++) {
            int h = p * 8 + i;
            float acc = 0.f;
#pragma unroll
            for (int mm = 0; mm < 8; mm++)
                acc = fmaf(P0[mi * 256 + mm * 32 + h], qv[mm], acc);
            OUT[mi * 256 + i * 32 + jl] = acc;
        }
        __syncthreads();
        {
            int hh = t >> 5, wj = t & 31;         // 8 rows x 32 cols
            int h = p * 8 + hh;
            float4 v0 = make_float4(OUT[t], OUT[256 + t], OUT[512 + t], OUT[768 + t]);
            float4 v1 = make_float4(OUT[1024 + t], OUT[1280 + t], OUT[1536 + t], OUT[1792 + t]);
            o4[obase + (size_t)(h * 256 + wj * 8)]     = v0;
            o4[obase + (size_t)(h * 256 + wj * 8) + 1] = v1;
        }
        if (p < 3) __syncthreads();   // stores read OUT before next pass rewrites
    }
}

extern "C" void kernel_launch(void* const* d_in, const int* in_sizes, int n_in,
                              void* d_out, int out_size, void* d_ws, size_t ws_size,
                              hipStream_t stream) {
    (void)in_sizes; (void)n_in; (void)out_size; (void)ws_size;
    const float* x = (const float*)d_in[0];
    const float* w = (const float*)d_in[1];
    float* out = (float*)d_out;
    float* uwd = (float*)d_ws;            // [32][32][8]
    float* vwt = uwd + 32 * 256;          // [32][32][8]

    hipLaunchKernelGGL(svd_w_kernel, dim3(16), dim3(64), 0, stream, w, uwd, vwt);
    hipLaunchKernelGGL(svd_main_kernel, dim3(4096), dim3(256), 0, stream, x, uwd, vwt, out);
}

// Round 21
// 751.763 us; speedup vs baseline: 4.9422x; 1.0339x over previous
//
#include <hip/hip_runtime.h>
#include <hip/hip_bf16.h>

#define NSWEEP_X 5
#define NSWEEP_W 9

typedef float v2f __attribute__((ext_vector_type(2)));

__device__ __forceinline__ void wavefence() {
    __builtin_amdgcn_wave_barrier();
    asm volatile("" ::: "memory");
}

// Packed fp32 (VOP3P) helpers — 2 fp32 per instruction.
__device__ __forceinline__ v2f pk_mul(v2f a, v2f b) {
    v2f d; asm("v_pk_mul_f32 %0, %1, %2" : "=v"(d) : "v"(a), "v"(b)); return d;
}
__device__ __forceinline__ v2f pk_add(v2f a, v2f b) {
    v2f d; asm("v_pk_add_f32 %0, %1, %2" : "=v"(d) : "v"(a), "v"(b)); return d;
}
__device__ __forceinline__ v2f pk_fma(v2f a, v2f b, v2f c) {
    v2f d; asm("v_pk_fma_f32 %0, %1, %2, %3" : "=v"(d) : "v"(a), "v"(b), "v"(c)); return d;
}

__device__ __forceinline__ float bperm(int addr, float v) {
    return __int_as_float(__builtin_amdgcn_ds_bpermute(addr, __float_as_int(v)));
}

// DPP xor-lane read: out[l] = in[l ^ mask] (masks<16 stay in 16-lane rows).
// Codes (r12/r14/r16/r18-verified): xor1=0xB1 xor2=0x4E xor3=0x1B xor7=0x141
// xor8=0x128(row_ror:8) xor15=0x140(row_mirror); composed pair = mask XOR.
// Pipe calibration (r16 k=9: 833us VALU-bound; r17 k=0: 991us DS-bound;
// r18 k=6: 753us balanced) -> k=6 is the optimum.
// Occupancy map (r18/r19/r20): launch_bounds(256,N) VGPR budget = 256/N;
// working set needs 64 -> N=4 is the unique no-spill maximum.
template<int C1, int C2>
__device__ __forceinline__ float dppf(float v) {
    int x = __builtin_amdgcn_mov_dpp(__float_as_int(v), C1, 0xF, 0xF, false);
    if constexpr (C2 >= 0)
        x = __builtin_amdgcn_mov_dpp(x, C2, 0xF, 0xF, false);
    return __int_as_float(x);
}

// 4-accumulator dot of two 32-float columns held as v2f[16].
__device__ __forceinline__ float dot32(const v2f a[16], const v2f b[16]) {
    v2f s0 = pk_mul(a[0], b[0]), s1 = pk_mul(a[1], b[1]);
    v2f s2 = pk_mul(a[2], b[2]), s3 = pk_mul(a[3], b[3]);
#pragma unroll
    for (int i = 4; i < 16; i += 4) {
        s0 = pk_fma(a[i+0], b[i+0], s0);
        s1 = pk_fma(a[i+1], b[i+1], s1);
        s2 = pk_fma(a[i+2], b[i+2], s2);
        s3 = pk_fma(a[i+3], b[i+3], s3);
    }
    v2f s = pk_add(pk_add(s0, s1), pk_add(s2, s3));
    return s.x + s.y;
}

// BRANCHLESS rotation core — r14/r16/r18-proven (64 VGPR, zero scratch).
// SPILL RULE (r3/r12/r15/r19/r20): prt[16] must be consumed in STRAIGHT-LINE
// code AND the VGPR bound must leave >=64 regs. Per-lane skip is v_cndmask
// only: t=0 -> cth=1, s=0 -> bitwise identity. No EXEC-mask writes (r13
// hazard: EXEC write before DPP read -> stale data).
// Local-tau (r7+): col' = c*col - s*prt, nn' = nn - t*cp, side-uniform;
// cp bitwise-equal across the pair -> symmetric decisions.
__device__ __forceinline__ int round_core(v2f col[16], const v2f prt[16],
                                          float& nn, float on, float thr) {
    float cp = dot32(col, prt);
    const bool rot = (cp * cp > thr);
    float tau = (on - nn) * __builtin_amdgcn_rcpf(2.0f * cp);
    float den = fabsf(tau) + __builtin_amdgcn_sqrtf(fmaf(tau, tau, 1.0f));
    float tt  = copysignf(__builtin_amdgcn_rcpf(den), tau);
    tt = rot ? tt : 0.0f;                              // v_cndmask, no EXEC write
    float cth = __builtin_amdgcn_rsqf(fmaf(tt, tt, 1.0f));   // tt=0 -> exactly 1.0
    float msn = tt * (-cth);
    v2f cs2; cs2.x = cth; cs2.y = cth;
    v2f ms2; ms2.x = msn; ms2.y = msn;
#pragma unroll
    for (int i = 0; i < 16; i++)
        col[i] = pk_fma(ms2, prt[i], pk_mul(cs2, col[i]));
    nn = fmaxf(fmaf(-tt, cp, nn), 0.0f);
    return rot ? 1 : 0;
}

// DPP round: partner fetch on the VALU pipe (zero DS ops). Fresh prt[16]
// per inlined body, consumed straight-line (SPILL RULE).
template<int C1, int C2>
__device__ __forceinline__ int round_dpp(v2f col[16], float& nn, float thr) {
    v2f prt[16];
#pragma unroll
    for (int i = 0; i < 16; i++) {
        prt[i].x = dppf<C1, C2>(col[i].x);
        prt[i].y = dppf<C1, C2>(col[i].y);
    }
    float on = dppf<C1, C2>(nn);
    return round_core(col, prt, nn, on, thr);
}

// bpermute round (DS pipe).
__device__ __forceinline__ int round_bperm(v2f col[16], float& nn, float thr,
                                           int lb, int m) {
    const int addr = lb ^ (m << 2);                    // within own 32-lane half
    v2f prt[16];
#pragma unroll
    for (int i = 0; i < 16; i++) {
        prt[i].x = bperm(addr, col[i].x);
        prt[i].y = bperm(addr, col[i].y);
    }
    float on = bperm(addr, nn);
    return round_core(col, prt, nn, on, thr);
}

// One-sided Jacobi, FULL column per lane, TWO matrices per wave (32-lane
// halves). XOR ordering over all m=1..31 (any fixed order = valid sweep).
// PIPE-BALANCED hybrid (r16/r17/r18 calibration): 6 single-op DPP
// {1,2,3,7,8,15} + 6 composed-DPP {4,5,6,9,10,11} on VALU; 19 masks
// {12,13,14,16..31} on DS via bpermute.
// Absolute skip threshold (4e-6*nmax)^2 above fp32 dot noise; all-skip
// early exit is a uniform SALU branch.
__device__ __forceinline__ void jacobi_hyb(v2f col[16], int lane, int nsweep) {
    const int lb = lane << 2;
    for (int sw = 0; sw < nsweep; ++sw) {
        float nn = dot32(col, col);
        float nmax = nn;
#pragma unroll
        for (int mk = 16; mk >= 1; mk >>= 1) nmax = fmaxf(nmax, __shfl_xor(nmax, mk));
        const float thr = 1.6e-11f * nmax * nmax;   // (4e-6 * nmax)^2

        int did = 0;
        did |= round_dpp<0xB1,  -1>(col, nn, thr);    // m=1
        did |= round_dpp<0x4E,  -1>(col, nn, thr);    // m=2
        did |= round_dpp<0x1B,  -1>(col, nn, thr);    // m=3
        did |= round_dpp<0x141, -1>(col, nn, thr);    // m=7
        did |= round_dpp<0x128, -1>(col, nn, thr);    // m=8
        did |= round_dpp<0x140, -1>(col, nn, thr);    // m=15
        did |= round_dpp<0x141, 0x1B>(col, nn, thr);  // m=4  (7^3)
        did |= round_dpp<0x141, 0x4E>(col, nn, thr);  // m=5  (7^2)
        did |= round_dpp<0x141, 0xB1>(col, nn, thr);  // m=6  (7^1)
        did |= round_dpp<0x128, 0xB1>(col, nn, thr);  // m=9  (8^1)
        did |= round_dpp<0x128, 0x4E>(col, nn, thr);  // m=10 (8^2)
        did |= round_dpp<0x128, 0x1B>(col, nn, thr);  // m=11 (8^3)
#pragma unroll 1
        for (int m = 12; m < 15; ++m)             // m=12,13,14
            did |= round_bperm(col, nn, thr, lb, m);
#pragma unroll 1
        for (int m = 16; m < 32; ++m)             // m=16..31
            did |= round_bperm(col, nn, thr, lb, m);

        if (!__any(did)) break;   // converged (uniform branch)
    }
}

// Rank own column by sigma^2 (descending, tie-break index) within the 32-lane
// group; rk<8 lanes pack their column into P0m[rk*32 + h], sigma^2 into sigm.
__device__ __forceinline__ void rank_pack2(const v2f col[16], int jl,
                                           float* P0m, float* nrmm, float* sigm) {
    float nn = dot32(col, col);
    nrmm[jl] = nn;
    wavefence();
    int rk = 0;
    for (int k = 0; k < 32; k++) {
        float o = nrmm[k];
        rk += (o > nn) || (o == nn && k < jl);
    }
    if (rk < 8) {
#pragma unroll
        for (int i = 0; i < 16; i++)
            *(v2f*)&P0m[rk * 32 + 2 * i] = col[i];
        sigm[rk] = nn;
    }
    wavefence();
}

// ---- Kernel 1: SVD of w[c]; one wave per block handles TWO c channels.
//   uwd[c][h][m] = Uw[h][m]*dw[m]   (converged column)
//   vwt[c][w][m] = Vwh[m][w]        (A0^T a_m / sigma_m^2)
__global__ __launch_bounds__(64)
void svd_w_kernel(const float* __restrict__ w, float* __restrict__ uwd,
                  float* __restrict__ vwt) {
    __shared__ float P0w[512];   // [hb*256 + mm*32 + h]
    __shared__ float nrmw[64];
    __shared__ float sigw[16];
    const int lane = threadIdx.x, jl = lane & 31, hb = lane >> 5;
    const int c = blockIdx.x * 2 + hb;

    v2f col[16], a0[16];
#pragma unroll
    for (int i = 0; i < 16; i++) {
        col[i].x = w[c * 1024 + (2 * i) * 32 + jl];
        col[i].y = w[c * 1024 + (2 * i + 1) * 32 + jl];
        a0[i] = col[i];
    }
    jacobi_hyb(col, lane, NSWEEP_W);
    rank_pack2(col, jl, P0w + hb * 256, nrmw + hb * 32, sigw + hb * 8);

    for (int e = jl; e < 256; e += 32)
        uwd[c * 256 + e] = P0w[hb * 256 + (e & 7) * 32 + (e >> 3)];

#pragma unroll
    for (int mm = 0; mm < 8; mm++) {
        v2f p[16];
#pragma unroll
        for (int i = 0; i < 16; i++) p[i] = *(const v2f*)&P0w[hb * 256 + mm * 32 + 2 * i];
        float vq = dot32(a0, p);
        vq *= __builtin_amdgcn_rcpf(sigw[hb * 8 + mm]);
        vwt[c * 256 + jl * 8 + mm] = vq;
    }
}

// ---- Kernel 2: block = 4 waves = 8 matrices (8 c of one bt). grid 4096.
// No LDS staging (global strided loads; input is L3-resident). a0 re-loaded
// from global after Jacobi -> no a0 liveness across the sweep.
// launch_bounds(256,4): the UNIQUE no-spill point (VGPR budget = 256/N;
// need 64 -> N=4). r19 (N=8, VGPR 32): 10 GB scratch, 5x slower.
// r20 (N=6, VGPR 40): mild spill, 777us. r18 (N=4, VGPR 64): 753us.
__global__ __launch_bounds__(256, 4)
void svd_main_kernel(const float* __restrict__ x, const float* __restrict__ uwd,
                     const float* __restrict__ vwt, float* __restrict__ out) {
    __shared__ float P0[2048];    // [mi*256 + mm*32 + h]
    __shared__ float nrm[256];    // [mi*32 + j]
    __shared__ float sig[64];     // [mi*8 + mm]
    __shared__ float OUT[2048];   // [mi*256 + i*32 + wj]  (8-row quarter-pass)

    const int t = threadIdx.x, widx = t >> 6, lane = t & 63;
    const int jl = lane & 31, hb = lane >> 5;
    const int bt = blockIdx.x & 1023, cg = blockIdx.x >> 10;
    const int mi = widx * 2 + hb, c = cg * 8 + mi;

    // own column straight from global: x[bt][h][jl][c], h stride 1024 floats
    const float* xb = x + (size_t)bt * 32768 + (size_t)jl * 32 + c;
    v2f col[16];
#pragma unroll
    for (int i = 0; i < 16; i++) {
        col[i].x = xb[(2 * i) * 1024];
        col[i].y = xb[(2 * i + 1) * 1024];
    }

    jacobi_hyb(col, lane, NSWEEP_X);
    rank_pack2(col, jl, P0 + mi * 256, nrm + mi * 32, sig + mi * 8);
    // col dead; re-load original column (L3-hot) for the V recovery

    v2f a0[16];
#pragma unroll
    for (int i = 0; i < 16; i++) {
        a0[i].x = xb[(2 * i) * 1024];
        a0[i].y = xb[(2 * i + 1) * 1024];
    }

    // qv[mm] = (A0^T a_mm / sigma^2) * vw   (lane jl = V-row index w)
    const float* vw = vwt + c * 256;
    const float* uw = uwd + c * 256;
    float qv[8];
#pragma unroll
    for (int mm = 0; mm < 8; mm++) {
        v2f p[16];
#pragma unroll
        for (int i = 0; i < 16; i++) p[i] = *(const v2f*)&P0[mi * 256 + mm * 32 + 2 * i];
        float vq = dot32(a0, p);
        vq *= __builtin_amdgcn_rcpf(sig[mi * 8 + mm]);
        qv[mm] = vq * vw[jl * 8 + mm];
    }

    // Pg in place: P0[mm*32+h] *= uw[h*8+mm]
    for (int e = jl; e < 256; e += 32)
        P0[mi * 256 + e] *= uw[(e & 31) * 8 + (e >> 5)];
    wavefence();

    // out[h][jl] = sum_mm Pg[h][mm]*qv[mm], in four 8-row quarter-passes.
    float4* o4 = (float4*)out;
    const size_t obase = (size_t)bt * 8192 + cg * 2;
    for (int p = 0; p < 4; ++p) {
#pragma unroll
        for (int i = 0; i < 8; i++) {
            int h = p * 8 + i;
            float acc = 0.f;
#pragma unroll
            for (int mm = 0; mm < 8; mm++)
                acc = fmaf(P0[mi * 256 + mm * 32 + h], qv[mm], acc);
            OUT[mi * 256 + i * 32 + jl] = acc;
        }
        __syncthreads();
        {
            int hh = t >> 5, wj = t & 31;         // 8 rows x 32 cols
            int h = p * 8 + hh;
            float4 v0 = make_float4(OUT[t], OUT[256 + t], OUT[512 + t], OUT[768 + t]);
            float4 v1 = make_float4(OUT[1024 + t], OUT[1280 + t], OUT[1536 + t], OUT[1792 + t]);
            o4[obase + (size_t)(h * 256 + wj * 8)]     = v0;
            o4[obase + (size_t)(h * 256 + wj * 8) + 1] = v1;
        }
        if (p < 3) __syncthreads();   // stores read OUT before next pass rewrites
    }
}

extern "C" void kernel_launch(void* const* d_in, const int* in_sizes, int n_in,
                              void* d_out, int out_size, void* d_ws, size_t ws_size,
                              hipStream_t stream) {
    (void)in_sizes; (void)n_in; (void)out_size; (void)ws_size;
    const float* x = (const float*)d_in[0];
    const float* w = (const float*)d_in[1];
    float* out = (float*)d_out;
    float* uwd = (float*)d_ws;            // [32][32][8]
    float* vwt = uwd + 32 * 256;          // [32][32][8]

    hipLaunchKernelGGL(svd_w_kernel, dim3(16), dim3(64), 0, stream, w, uwd, vwt);
    hipLaunchKernelGGL(svd_main_kernel, dim3(4096), dim3(256), 0, stream, x, uwd, vwt, out);
}